// Round 1
// baseline (390.159 us; speedup 1.0000x reference)
//
#include <hip/hip_runtime.h>
#include <math.h>

#define NT 262144
#define KD 512
#define NE 64
#define DE 64

constexpr int BM = 128;   // tokens per block
constexpr int BK = 32;    // K tile
constexpr int LA = 132;   // LDS stride for [k][tok] / [d][tok]  (528B, 16B-aligned)
constexpr int LB = 68;    // LDS stride for [k][col] / [d][expert]

__device__ __forceinline__ float f4c(const float4 v, int j) {
    return j == 0 ? v.x : (j == 1 ? v.y : (j == 2 ? v.z : v.w));
}

// Fused: proj GEMM -> row norm -> cosine scores -> softmax -> top2.
// 128 threads/block, 8x8 register tile per thread: 64 FMA per 64B of LDS reads
// (1.0 B/FMA vs 1.5 B/FMA before) -- stage-1 is LDS-read-throughput bound.
__global__ __launch_bounds__(128) void moe_all(const float* __restrict__ h,
                                               const float* __restrict__ W,
                                               const float* __restrict__ E,
                                               const float* __restrict__ tau_p,
                                               float* __restrict__ out) {
    // stage1: rows 0..31 = h tile [k][tok]; stage2: h_norm [d][tok]
    __shared__ float s_hn[DE * LA];
    // stage1: rows 0..31 = W tile [k][col]; stage2: e_norm [d][e]
    __shared__ float s_we[DE * LB];

    const int tid = threadIdx.x;
    const int tx = tid & 7;    // expert-col group: cols tx*8 + j
    const int ty = tid >> 3;   // token group: tokens ty*8 + i  (0..15)
    const long tok0 = (long)blockIdx.x * BM;

    float acc[8][8];
    #pragma unroll
    for (int i = 0; i < 8; ++i)
        #pragma unroll
        for (int j = 0; j < 8; ++j) acc[i][j] = 0.0f;

    // staging mapping: kq = k-quad (0..7), tg = token-group (8 tok) / col-group (4 cols)
    const int kq = tid & 7;
    const int tg = tid >> 3;

    float4 rh[8], rw[4];
    // prefetch K-tile 0
    #pragma unroll
    for (int i = 0; i < 8; ++i)
        rh[i] = *(const float4*)(h + (tok0 + tg * 8 + i) * KD + kq * 4);
    #pragma unroll
    for (int c = 0; c < 4; ++c)
        rw[c] = *(const float4*)(W + (size_t)(tg * 4 + c) * KD + kq * 4);

    // ---------------- stage 1: proj[128][64] = h_tile @ W^T ----------------
    for (int t = 0; t < KD / BK; ++t) {
        __syncthreads();
        // in-register 8x4 / 4x4 transpose, b128 LDS writes, even bank spread
        #pragma unroll
        for (int j = 0; j < 4; ++j) {
            float* dh = s_hn + (kq * 4 + j) * LA + tg * 8;
            *(float4*)dh =
                make_float4(f4c(rh[0], j), f4c(rh[1], j), f4c(rh[2], j), f4c(rh[3], j));
            *(float4*)(dh + 4) =
                make_float4(f4c(rh[4], j), f4c(rh[5], j), f4c(rh[6], j), f4c(rh[7], j));
            *(float4*)(s_we + (kq * 4 + j) * LB + tg * 4) =
                make_float4(f4c(rw[0], j), f4c(rw[1], j), f4c(rw[2], j), f4c(rw[3], j));
        }
        __syncthreads();
        if (t + 1 < KD / BK) {  // register prefetch hides HBM latency
            const int k0 = (t + 1) * BK;
            #pragma unroll
            for (int i = 0; i < 8; ++i)
                rh[i] = *(const float4*)(h + (tok0 + tg * 8 + i) * KD + k0 + kq * 4);
            #pragma unroll
            for (int c = 0; c < 4; ++c)
                rw[c] = *(const float4*)(W + (size_t)(tg * 4 + c) * KD + k0 + kq * 4);
        }
        #pragma unroll 4
        for (int kk = 0; kk < BK; ++kk) {
            const float* ra = s_hn + kk * LA + ty * 8;
            const float* rb = s_we + kk * LB + tx * 8;
            float4 a0 = *(const float4*)ra;        // 8-lane broadcast, 2-way: free
            float4 a1 = *(const float4*)(ra + 4);
            float4 b0 = *(const float4*)rb;
            float4 b1 = *(const float4*)(rb + 4);
            float av[8] = {a0.x, a0.y, a0.z, a0.w, a1.x, a1.y, a1.z, a1.w};
            float bv[8] = {b0.x, b0.y, b0.z, b0.w, b1.x, b1.y, b1.z, b1.w};
            #pragma unroll
            for (int i = 0; i < 8; ++i)
                #pragma unroll
                for (int j = 0; j < 8; ++j)
                    acc[i][j] = fmaf(av[i], bv[j], acc[i][j]);
        }
    }

    // ---------------- per-token L2 norm (in-register, 8-lane shuffle) -------
    float inv_n[8];
    #pragma unroll
    for (int i = 0; i < 8; ++i) {
        float ss = 0.f;
        #pragma unroll
        for (int j = 0; j < 8; ++j) ss = fmaf(acc[i][j], acc[i][j], ss);
        ss += __shfl_xor(ss, 1, 64);
        ss += __shfl_xor(ss, 2, 64);
        ss += __shfl_xor(ss, 4, 64);
        inv_n[i] = 1.0f / fmaxf(sqrtf(ss), 1e-12f);
    }

    __syncthreads();  // stage-1 LDS reads complete; safe to repurpose buffers

    // h_norm -> s_hn as [d][tok], vectorized along tokens (b128 writes)
    #pragma unroll
    for (int j = 0; j < 8; ++j) {
        float* dst = s_hn + (tx * 8 + j) * LA + ty * 8;
        *(float4*)dst = make_float4(acc[0][j] * inv_n[0], acc[1][j] * inv_n[1],
                                    acc[2][j] * inv_n[2], acc[3][j] * inv_n[3]);
        *(float4*)(dst + 4) = make_float4(acc[4][j] * inv_n[4], acc[5][j] * inv_n[5],
                                          acc[6][j] * inv_n[6], acc[7][j] * inv_n[7]);
    }

    // e_norm -> s_we as [d][e]; E is 16KB, L2-hot, recomputed per block
    {
        const int er = tid >> 1, part = tid & 1;
        float ss = 0.f;
        float4 ev[8];
        #pragma unroll
        for (int u = 0; u < 8; ++u) {
            ev[u] = *(const float4*)(E + er * DE + part * 32 + u * 4);
            ss = fmaf(ev[u].x, ev[u].x, ss);
            ss = fmaf(ev[u].y, ev[u].y, ss);
            ss = fmaf(ev[u].z, ev[u].z, ss);
            ss = fmaf(ev[u].w, ev[u].w, ss);
        }
        ss += __shfl_xor(ss, 1, 64);
        const float inv_e = 1.0f / fmaxf(sqrtf(ss), 1e-12f);
        #pragma unroll
        for (int u = 0; u < 8; ++u) {
            const int d = part * 32 + u * 4;
            s_we[(d + 0) * LB + er] = ev[u].x * inv_e;
            s_we[(d + 1) * LB + er] = ev[u].y * inv_e;
            s_we[(d + 2) * LB + er] = ev[u].z * inv_e;
            s_we[(d + 3) * LB + er] = ev[u].w * inv_e;
        }
    }
    __syncthreads();

    // ---------------- stage 2: scores[128][64] = h_norm @ e_norm^T (K=64) ---
    #pragma unroll
    for (int i = 0; i < 8; ++i)
        #pragma unroll
        for (int j = 0; j < 8; ++j) acc[i][j] = 0.0f;

    #pragma unroll 4
    for (int dd = 0; dd < DE; ++dd) {
        const float* ra = s_hn + dd * LA + ty * 8;
        const float* rb = s_we + dd * LB + tx * 8;
        float4 a0 = *(const float4*)ra;
        float4 a1 = *(const float4*)(ra + 4);
        float4 b0 = *(const float4*)rb;
        float4 b1 = *(const float4*)(rb + 4);
        float av[8] = {a0.x, a0.y, a0.z, a0.w, a1.x, a1.y, a1.z, a1.w};
        float bv[8] = {b0.x, b0.y, b0.z, b0.w, b1.x, b1.y, b1.z, b1.w};
        #pragma unroll
        for (int i = 0; i < 8; ++i)
            #pragma unroll
            for (int j = 0; j < 8; ++j)
                acc[i][j] = fmaf(av[i], bv[j], acc[i][j]);
    }

    // ---------------- epilogue: softmax, top-2, outputs ----------------------
    const float inv_tau = 1.0f / tau_p[0];
    float* outS = out;                        // sparse_gates [NT][64]
    float* outI = out + (size_t)NT * 64;      // topk_indices [NT][2] (as float)
    float* outF = out + (size_t)NT * 66;      // full_gates   [NT][64]

    #pragma unroll
    for (int i = 0; i < 8; ++i) {
        const long tok = tok0 + ty * 8 + i;
        float s[8];
        #pragma unroll
        for (int j = 0; j < 8; ++j) s[j] = acc[i][j] * inv_tau;

        float m = s[0];
        #pragma unroll
        for (int j = 1; j < 8; ++j) m = fmaxf(m, s[j]);
        m = fmaxf(m, __shfl_xor(m, 1, 64));
        m = fmaxf(m, __shfl_xor(m, 2, 64));
        m = fmaxf(m, __shfl_xor(m, 4, 64));

        float g[8], z = 0.f;
        #pragma unroll
        for (int j = 0; j < 8; ++j) { g[j] = __expf(s[j] - m); z += g[j]; }
        z += __shfl_xor(z, 1, 64);
        z += __shfl_xor(z, 2, 64);
        z += __shfl_xor(z, 4, 64);
        const float invZ = 1.0f / z;

        *(float4*)(outF + tok * 64 + tx * 8) =
            make_float4(g[0] * invZ, g[1] * invZ, g[2] * invZ, g[3] * invZ);
        *(float4*)(outF + tok * 64 + tx * 8 + 4) =
            make_float4(g[4] * invZ, g[5] * invZ, g[6] * invZ, g[7] * invZ);

        // top-2 on s (monotone with gates); ties -> lower index (jax top_k)
        float v1 = -3.4e38f, v2 = -3.4e38f;
        int i1 = 1 << 20, i2 = 1 << 20;
        #pragma unroll
        for (int j = 0; j < 8; ++j) {
            float v = s[j];
            int e = tx * 8 + j;
            if (v > v1 || (v == v1 && e < i1)) { v2 = v1; i2 = i1; v1 = v; i1 = e; }
            else if (v > v2 || (v == v2 && e < i2)) { v2 = v; i2 = e; }
        }
        #pragma unroll
        for (int msk = 1; msk <= 4; msk <<= 1) {
            float o1 = __shfl_xor(v1, msk, 64); int oi1 = __shfl_xor(i1, msk, 64);
            float o2 = __shfl_xor(v2, msk, 64); int oi2 = __shfl_xor(i2, msk, 64);
            if (o1 > v1 || (o1 == v1 && oi1 < i1)) {
                if (v1 > o2 || (v1 == o2 && i1 < oi2)) { v2 = v1; i2 = i1; }
                else { v2 = o2; i2 = oi2; }
                v1 = o1; i1 = oi1;
            } else {
                if (o1 > v2 || (o1 == v2 && oi1 < i2)) { v2 = o1; i2 = oi1; }
            }
        }

        // softmax over the two top GATE values
        float gv1 = __expf(v1 - m) * invZ;
        float gv2 = __expf(v2 - m) * invZ;
        float qq = __expf(gv2 - gv1);
        float w1 = 1.0f / (1.0f + qq);
        float w2 = qq * w1;

        float sp[8];
        #pragma unroll
        for (int j = 0; j < 8; ++j) {
            int e = tx * 8 + j;
            sp[j] = (e == i1) ? w1 : ((e == i2) ? w2 : 0.0f);
        }
        *(float4*)(outS + tok * 64 + tx * 8) = make_float4(sp[0], sp[1], sp[2], sp[3]);
        *(float4*)(outS + tok * 64 + tx * 8 + 4) = make_float4(sp[4], sp[5], sp[6], sp[7]);
        if (tx == 0) {
            *(float2*)(outI + tok * 2) = make_float2((float)i1, (float)i2);
        }
    }
}

extern "C" void kernel_launch(void* const* d_in, const int* in_sizes, int n_in,
                              void* d_out, int out_size, void* d_ws, size_t ws_size,
                              hipStream_t stream) {
    const float* h   = (const float*)d_in[0];
    const float* W   = (const float*)d_in[1];
    const float* E   = (const float*)d_in[2];
    const float* tau = (const float*)d_in[3];
    float* out = (float*)d_out;

    moe_all<<<NT / BM, 128, 0, stream>>>(h, W, E, tau, out);
}

// Round 2
// 285.860 us; speedup vs baseline: 1.3649x; 1.3649x over previous
//
#include <hip/hip_runtime.h>
#include <math.h>

#define NT 262144
#define KD 512
#define NE 64
#define DE 64

constexpr int BM = 128;   // tokens per block
constexpr int LA = 132;   // LDS stride for h_norm [d][tok]
constexpr int LB = 68;    // LDS stride for e_norm [d][e]

using f32x4 = __attribute__((ext_vector_type(4))) float;
using s16x8 = __attribute__((ext_vector_type(8))) short;

// ---- 3-term truncated bf16 split of fp32: x = x1 + x2 + x3, |res| <= 2^-24|x| ----
// Packs two consecutive elements per u32 (low short = even elem).
__device__ __forceinline__ void split8(float4 lo, float4 hi,
                                       s16x8& o1, s16x8& o2, s16x8& o3) {
    float x[8] = {lo.x, lo.y, lo.z, lo.w, hi.x, hi.y, hi.z, hi.w};
    union { unsigned int u[4]; s16x8 v; } r1, r2, r3;
    #pragma unroll
    for (int p = 0; p < 4; ++p) {
        float f0 = x[2 * p], f1 = x[2 * p + 1];
        unsigned int a = __float_as_uint(f0), b = __float_as_uint(f1);
        unsigned int a1 = a & 0xFFFF0000u, b1 = b & 0xFFFF0000u;
        r1.u[p] = (a1 >> 16) | b1;
        float q0 = f0 - __uint_as_float(a1);
        float q1 = f1 - __uint_as_float(b1);
        unsigned int a2 = __float_as_uint(q0) & 0xFFFF0000u;
        unsigned int b2 = __float_as_uint(q1) & 0xFFFF0000u;
        r2.u[p] = (a2 >> 16) | b2;
        float s0 = q0 - __uint_as_float(a2);
        float s1 = q1 - __uint_as_float(b2);
        r3.u[p] = (__float_as_uint(s0) >> 16) | (__float_as_uint(s1) & 0xFFFF0000u);
    }
    o1 = r1.v; o2 = r2.v; o3 = r3.v;
}

__device__ __forceinline__ s16x8 ld_frag(const unsigned int* p) {
    union { uint4 q; s16x8 v; } u;
    u.q = *(const uint4*)p;
    return u.v;
}

// ---- prep: split W [64][512] fp32 into 3 bf16 planes in workspace ----
__global__ void prep_splitW(const float* __restrict__ W, unsigned int* __restrict__ ws) {
    const int p = blockIdx.x * 256 + threadIdx.x;  // pair index, 16384 total
    const float f0 = W[2 * p], f1 = W[2 * p + 1];
    unsigned int a = __float_as_uint(f0), b = __float_as_uint(f1);
    unsigned int a1 = a & 0xFFFF0000u, b1 = b & 0xFFFF0000u;
    float q0 = f0 - __uint_as_float(a1);
    float q1 = f1 - __uint_as_float(b1);
    unsigned int a2 = __float_as_uint(q0) & 0xFFFF0000u;
    unsigned int b2 = __float_as_uint(q1) & 0xFFFF0000u;
    float s0 = q0 - __uint_as_float(a2);
    float s1 = q1 - __uint_as_float(b2);
    ws[p]         = (a1 >> 16) | b1;
    ws[16384 + p] = (a2 >> 16) | b2;
    ws[32768 + p] = (__float_as_uint(s0) >> 16) | (__float_as_uint(s1) & 0xFFFF0000u);
}

// ---- fused main: MFMA split-bf16 proj -> norm -> scores -> softmax -> top2 ----
// Stage-1 K-loop has NO LDS and NO barriers: A-fragments load straight from
// global h (coalesced 128B/row), split in-register; B-fragments from the
// precomputed W-splits (L1/L2-hot). One __syncthreads per block total.
__global__ __launch_bounds__(256, 3) void moe_all(const float* __restrict__ h,
                                                  const unsigned int* __restrict__ wsW,
                                                  const float* __restrict__ E,
                                                  const float* __restrict__ tau_p,
                                                  float* __restrict__ out) {
    __shared__ float s_hn[DE * LA];   // stage2: h_norm [d][tok]
    __shared__ float s_we[DE * LB];   // stage2: e_norm [d][e]

    const int tid = threadIdx.x;
    const int lane = tid & 63;
    const int wv = tid >> 6;          // wave 0..3 -> tokens [wv*32, wv*32+32)
    const int lr = lane & 15;         // fragment row/col within 16
    const int lk = lane >> 4;         // k-group 0..3
    const long tok0 = (long)blockIdx.x * BM;
    const long wtok = tok0 + wv * 32;

    f32x4 acc[2][4];                  // [row-tile][col-tile], 16x16 each
    #pragma unroll
    for (int rt = 0; rt < 2; ++rt)
        #pragma unroll
        for (int ct = 0; ct < 4; ++ct)
            acc[rt][ct] = (f32x4){0.f, 0.f, 0.f, 0.f};

    // A base pointers: lane reads h[wtok + rt*16 + lr][k..k+8)
    const float* pa0 = h + (wtok + 0 * 16 + lr) * (long)KD + lk * 8;
    const float* pa1 = h + (wtok + 1 * 16 + lr) * (long)KD + lk * 8;

    float4 alo[2], ahi[2];
    alo[0] = *(const float4*)(pa0);     ahi[0] = *(const float4*)(pa0 + 4);
    alo[1] = *(const float4*)(pa1);     ahi[1] = *(const float4*)(pa1 + 4);

    for (int ks = 0; ks < KD / 32; ++ks) {
        float4 nlo[2], nhi[2];
        if (ks + 1 < KD / 32) {  // prefetch next K-step (hides HBM latency)
            const int o = (ks + 1) * 32;
            nlo[0] = *(const float4*)(pa0 + o); nhi[0] = *(const float4*)(pa0 + o + 4);
            nlo[1] = *(const float4*)(pa1 + o); nhi[1] = *(const float4*)(pa1 + o + 4);
        }
        s16x8 a1[2], a2[2], a3[2];
        split8(alo[0], ahi[0], a1[0], a2[0], a3[0]);
        split8(alo[1], ahi[1], a1[1], a2[1], a3[1]);

        const int kb = ks * 32 + lk * 8;
        #pragma unroll
        for (int ct = 0; ct < 4; ++ct) {
            const int bi = ((ct * 16 + lr) * KD + kb) >> 1;   // u32 index
            s16x8 b1 = ld_frag(wsW + bi);
            s16x8 b2 = ld_frag(wsW + 16384 + bi);
            s16x8 b3 = ld_frag(wsW + 32768 + bi);
            #pragma unroll
            for (int rt = 0; rt < 2; ++rt) {
                f32x4 c = acc[rt][ct];
                c = __builtin_amdgcn_mfma_f32_16x16x32_bf16(a1[rt], b1, c, 0, 0, 0);
                c = __builtin_amdgcn_mfma_f32_16x16x32_bf16(a2[rt], b1, c, 0, 0, 0);
                c = __builtin_amdgcn_mfma_f32_16x16x32_bf16(a1[rt], b2, c, 0, 0, 0);
                c = __builtin_amdgcn_mfma_f32_16x16x32_bf16(a3[rt], b1, c, 0, 0, 0);
                c = __builtin_amdgcn_mfma_f32_16x16x32_bf16(a2[rt], b2, c, 0, 0, 0);
                c = __builtin_amdgcn_mfma_f32_16x16x32_bf16(a1[rt], b3, c, 0, 0, 0);
                acc[rt][ct] = c;
            }
        }
        alo[0] = nlo[0]; ahi[0] = nhi[0];
        alo[1] = nlo[1]; ahi[1] = nhi[1];
    }

    // ---- per-token L2 norm from fragments ----
    // C/D layout: col = lane&15 (d), row = (lane>>4)*4 + reg (token within 16)
    float inv_n[2][4];
    #pragma unroll
    for (int rt = 0; rt < 2; ++rt) {
        #pragma unroll
        for (int r = 0; r < 4; ++r) {
            float ss = 0.f;
            #pragma unroll
            for (int ct = 0; ct < 4; ++ct)
                ss = fmaf(acc[rt][ct][r], acc[rt][ct][r], ss);
            ss += __shfl_xor(ss, 1, 64);
            ss += __shfl_xor(ss, 2, 64);
            ss += __shfl_xor(ss, 4, 64);
            ss += __shfl_xor(ss, 8, 64);
            inv_n[rt][r] = 1.0f / fmaxf(sqrtf(ss), 1e-12f);
        }
    }

    // h_norm -> LDS [d][tok] (one-time scatter; outside all loops)
    #pragma unroll
    for (int rt = 0; rt < 2; ++rt)
        #pragma unroll
        for (int ct = 0; ct < 4; ++ct)
            #pragma unroll
            for (int r = 0; r < 4; ++r) {
                const int d = ct * 16 + lr;
                const int t = wv * 32 + rt * 16 + lk * 4 + r;
                s_hn[d * LA + t] = acc[rt][ct][r] * inv_n[rt][r];
            }

    // e_norm -> s_we as [d][e]; E is 16KB, L2-hot
    {
        const int er = tid >> 2, part = tid & 3;
        float ss = 0.f;
        float4 ev[4];
        #pragma unroll
        for (int u = 0; u < 4; ++u) {
            ev[u] = *(const float4*)(E + er * DE + part * 16 + u * 4);
            ss = fmaf(ev[u].x, ev[u].x, ss);
            ss = fmaf(ev[u].y, ev[u].y, ss);
            ss = fmaf(ev[u].z, ev[u].z, ss);
            ss = fmaf(ev[u].w, ev[u].w, ss);
        }
        ss += __shfl_xor(ss, 1, 64);
        ss += __shfl_xor(ss, 2, 64);
        const float inv_e = 1.0f / fmaxf(sqrtf(ss), 1e-12f);
        #pragma unroll
        for (int u = 0; u < 4; ++u) {
            int d = part * 16 + u * 4;
            s_we[(d + 0) * LB + er] = ev[u].x * inv_e;
            s_we[(d + 1) * LB + er] = ev[u].y * inv_e;
            s_we[(d + 2) * LB + er] = ev[u].z * inv_e;
            s_we[(d + 3) * LB + er] = ev[u].w * inv_e;
        }
    }
    __syncthreads();   // the only block barrier

    // ---- stage 2: scores[128][64] = h_norm @ e_norm^T (K=64), fp32 VALU ----
    const int tx = tid & 15;   // cols tx*4 + j
    const int ty = tid >> 4;   // tokens p*64 + ty*4 + i
    float sacc[2][4][4];
    #pragma unroll
    for (int p = 0; p < 2; ++p)
        #pragma unroll
        for (int i = 0; i < 4; ++i)
            #pragma unroll
            for (int j = 0; j < 4; ++j) sacc[p][i][j] = 0.0f;

    #pragma unroll 8
    for (int dd = 0; dd < DE; ++dd) {
        const float* ra = s_hn + dd * LA;
        const float* rb = s_we + dd * LB;
        float4 a0 = *(const float4*)(ra + ty * 4);
        float4 a1v = *(const float4*)(ra + 64 + ty * 4);
        float4 b  = *(const float4*)(rb + tx * 4);
        float av[2][4] = {{a0.x, a0.y, a0.z, a0.w}, {a1v.x, a1v.y, a1v.z, a1v.w}};
        float bv[4] = {b.x, b.y, b.z, b.w};
        #pragma unroll
        for (int p = 0; p < 2; ++p)
            #pragma unroll
            for (int i = 0; i < 4; ++i)
                #pragma unroll
                for (int j = 0; j < 4; ++j)
                    sacc[p][i][j] = fmaf(av[p][i], bv[j], sacc[p][i][j]);
    }

    // ---- epilogue: softmax, top-2, outputs ----
    const float inv_tau = 1.0f / tau_p[0];
    float* outS = out;                        // sparse_gates [NT][64]
    float* outI = out + (size_t)NT * 64;      // topk_indices [NT][2] (as float)
    float* outF = out + (size_t)NT * 66;      // full_gates   [NT][64]

    #pragma unroll
    for (int p = 0; p < 2; ++p) {
        #pragma unroll
        for (int i = 0; i < 4; ++i) {
            const long tok = tok0 + p * 64 + ty * 4 + i;
            float s[4];
            #pragma unroll
            for (int j = 0; j < 4; ++j) s[j] = sacc[p][i][j] * inv_tau;

            float m = fmaxf(fmaxf(s[0], s[1]), fmaxf(s[2], s[3]));
            m = fmaxf(m, __shfl_xor(m, 1, 64));
            m = fmaxf(m, __shfl_xor(m, 2, 64));
            m = fmaxf(m, __shfl_xor(m, 4, 64));
            m = fmaxf(m, __shfl_xor(m, 8, 64));

            float g[4], z = 0.f;
            #pragma unroll
            for (int j = 0; j < 4; ++j) { g[j] = __expf(s[j] - m); z += g[j]; }
            z += __shfl_xor(z, 1, 64);
            z += __shfl_xor(z, 2, 64);
            z += __shfl_xor(z, 4, 64);
            z += __shfl_xor(z, 8, 64);
            const float invZ = 1.0f / z;

            *(float4*)(outF + tok * 64 + tx * 4) =
                make_float4(g[0] * invZ, g[1] * invZ, g[2] * invZ, g[3] * invZ);

            // top-2 on s (monotone with gates); ties -> lower index (jax top_k)
            float v1 = -3.4e38f, v2 = -3.4e38f;
            int i1 = 1 << 20, i2 = 1 << 20;
            #pragma unroll
            for (int j = 0; j < 4; ++j) {
                float v = s[j];
                int e = tx * 4 + j;
                if (v > v1 || (v == v1 && e < i1)) { v2 = v1; i2 = i1; v1 = v; i1 = e; }
                else if (v > v2 || (v == v2 && e < i2)) { v2 = v; i2 = e; }
            }
            #pragma unroll
            for (int msk = 1; msk <= 8; msk <<= 1) {
                float o1 = __shfl_xor(v1, msk, 64); int oi1 = __shfl_xor(i1, msk, 64);
                float o2 = __shfl_xor(v2, msk, 64); int oi2 = __shfl_xor(i2, msk, 64);
                if (o1 > v1 || (o1 == v1 && oi1 < i1)) {
                    if (v1 > o2 || (v1 == o2 && i1 < oi2)) { v2 = v1; i2 = i1; }
                    else { v2 = o2; i2 = oi2; }
                    v1 = o1; i1 = oi1;
                } else {
                    if (o1 > v2 || (o1 == v2 && oi1 < i2)) { v2 = o1; i2 = oi1; }
                }
            }

            // softmax over the two top GATE values
            float gv1 = __expf(v1 - m) * invZ;
            float gv2 = __expf(v2 - m) * invZ;
            float qq = __expf(gv2 - gv1);
            float w1 = 1.0f / (1.0f + qq);
            float w2 = qq * w1;

            float sp[4];
            #pragma unroll
            for (int j = 0; j < 4; ++j) {
                int e = tx * 4 + j;
                sp[j] = (e == i1) ? w1 : ((e == i2) ? w2 : 0.0f);
            }
            *(float4*)(outS + tok * 64 + tx * 4) = make_float4(sp[0], sp[1], sp[2], sp[3]);
            if (tx == 0) {
                *(float2*)(outI + tok * 2) = make_float2((float)i1, (float)i2);
            }
        }
    }
}

extern "C" void kernel_launch(void* const* d_in, const int* in_sizes, int n_in,
                              void* d_out, int out_size, void* d_ws, size_t ws_size,
                              hipStream_t stream) {
    const float* h   = (const float*)d_in[0];
    const float* W   = (const float*)d_in[1];
    const float* E   = (const float*)d_in[2];
    const float* tau = (const float*)d_in[3];
    float* out = (float*)d_out;
    unsigned int* ws = (unsigned int*)d_ws;   // 192 KB: W1|W2|W3 bf16 planes

    prep_splitW<<<64, 256, 0, stream>>>(W, ws);
    moe_all<<<NT / BM, 256, 0, stream>>>(h, ws, E, tau, out);
}